// Round 3
// baseline (2141.085 us; speedup 1.0000x reference)
//
#include <hip/hip_runtime.h>
#include <hip/hip_bf16.h>

typedef short bf16x8 __attribute__((ext_vector_type(8)));
typedef float f32x4 __attribute__((ext_vector_type(4)));

#define NH_ 12
#define DIM_ 384
#define WCHUNK 128   // windows per chunk (2048 total / 16 chunks)

static __device__ __forceinline__ float bf2f_us(ushort u) {
    __hip_bfloat16 h; __builtin_memcpy(&h, &u, 2);
    return __bfloat162float(h);
}
static __device__ __forceinline__ ushort f2us(float f) {
    __hip_bfloat16 h = __float2bfloat16(f);
    ushort u; __builtin_memcpy(&u, &h, 2);
    return u;
}

static __device__ __forceinline__ int regioncnt(int t, int wr, int wc) {
    int rr = (wr == 7) ? (((t >> 3) < 4) ? 1 : 2) : 0;
    int cc = (wc == 7) ? (((t & 7) < 4) ? 1 : 2) : 0;
    return rr * 3 + cc;
}

// ---------------- dtype detector: 1 = inputs are f32, 0 = inputs are bf16 ----------------
__global__ void detect_kernel(const ushort* __restrict__ x, int* __restrict__ flag) {
    int lane = threadIdx.x;
    int big = 0;
    for (int i = lane; i < 32768; i += 64) {
        float v = bf2f_us(x[i]);
        float av = fabsf(v);
        if (av > 1e4f || v != v) big = 1;
    }
    unsigned long long m = __ballot(big);
    if (lane == 0) *flag = (m != 0ull) ? 1 : 0;
}

// ---------------- normalize weights/biases/table to bf16 in ws ----------------
// dst layout (ushort elements): wq[147456] wk wv wo | bq[384] bk bv bo | table[2700]
__global__ __launch_bounds__(256) void convert_kernel(
    const void* wq, const void* wk, const void* wv, const void* wo,
    const void* bq, const void* bk, const void* bv, const void* bo,
    const void* bt, const int* __restrict__ flag, ushort* __restrict__ dst)
{
    const int isf32 = *flag;
    const int N = 594060;
    for (int i = blockIdx.x * 256 + threadIdx.x; i < N; i += gridDim.x * 256) {
        const void* src; int off;
        if (i < 589824) {
            int wsel = i / 147456; off = i - wsel * 147456;
            src = (wsel == 0) ? wq : (wsel == 1) ? wk : (wsel == 2) ? wv : wo;
        } else if (i < 591360) {
            int bsel = (i - 589824) / 384; off = (i - 589824) - bsel * 384;
            src = (bsel == 0) ? bq : (bsel == 1) ? bk : (bsel == 2) ? bv : bo;
        } else {
            off = i - 591360; src = bt;
        }
        ushort u;
        if (isf32) u = f2us(((const float*)src)[off]);
        else       u = ((const ushort*)src)[off];
        dst[i] = u;
    }
}

// ---------------- relative-position bias matrix (12,64,64) fp32 ----------------
__global__ void bias_kernel(const ushort* __restrict__ tablec, float* __restrict__ biasmat) {
    int i = blockIdx.x;   // row token
    int j = threadIdx.x;  // col token
    int idx = ((i >> 3) - (j >> 3) + 7) * 15 + ((i & 7) - (j & 7) + 7);
    #pragma unroll
    for (int h = 0; h < NH_; ++h)
        biasmat[h * 4096 + i * 64 + j] = bf2f_us(tablec[idx * NH_ + h]);
}

// ---------------- QKV projection per window (chunked) ----------------
__global__ __launch_bounds__(256) void qkv_kernel(
    const void* __restrict__ x, const ushort* __restrict__ wb,
    const int* __restrict__ flag,
    __hip_bfloat16* __restrict__ qws, __hip_bfloat16* __restrict__ kws,
    __hip_bfloat16* __restrict__ vws, int wbase)
{
    __shared__ __align__(16) ushort As[64 * 392];
    const int lw = blockIdx.x;
    const int w = wbase + lw;
    const int b = w >> 6, widx = w & 63, wr = widx >> 3, wc = widx & 7;
    const int tid = threadIdx.x;
    const int isf32 = *flag;

    if (isf32) {
        const float* xf = (const float*)x;
        for (int c = tid; c < 64 * 96; c += 256) {   // 4 floats per chunk
            int token = c / 96, chunk = c - token * 96;
            int orr = (wr * 8 + (token >> 3) + 4) & 63;
            int occ = (wc * 8 + (token & 7) + 4) & 63;
            const float4 v = *reinterpret_cast<const float4*>(
                xf + (((size_t)b * 64 + orr) * 64 + occ) * DIM_ + chunk * 4);
            ushort* d = &As[token * 392 + chunk * 4];
            d[0] = f2us(v.x); d[1] = f2us(v.y); d[2] = f2us(v.z); d[3] = f2us(v.w);
        }
    } else {
        const ushort* xb = (const ushort*)x;
        for (int c = tid; c < 64 * 48; c += 256) {   // 8 bf16 per chunk
            int token = c / 48, chunk = c - token * 48;
            int orr = (wr * 8 + (token >> 3) + 4) & 63;
            int occ = (wc * 8 + (token & 7) + 4) & 63;
            *reinterpret_cast<uint4*>(&As[token * 392 + chunk * 8]) =
                *reinterpret_cast<const uint4*>(
                    xb + (((size_t)b * 64 + orr) * 64 + occ) * DIM_ + chunk * 8);
        }
    }
    __syncthreads();

    const int lane = tid & 63, wave = tid >> 6;
    const int col16 = lane & 15, quad = lane >> 4;
    const float scale = 0.17677669529663687f;  // 32^-0.5
    const ushort* bias_all = wb + 589824;      // bq,bk,bv,bo each 384

    for (int s = wave; s < 72; s += 4) {  // [0,24)=q [24,48)=k [48,72)=v
        const int wsel = s / 24;
        const int j0 = (s - wsel * 24) * 16;
        const ushort* W = wb + (size_t)wsel * 147456;        // wq,wk,wv
        const ushort* bb = bias_all + wsel * 384;
        const int j = j0 + col16;
        const ushort* wrow = W + (size_t)j * DIM_ + quad * 8;
        const int abase = col16 * 392 + quad * 8;
        f32x4 acc0 = {0.f,0.f,0.f,0.f}, acc1 = acc0, acc2 = acc0, acc3 = acc0;
        #pragma unroll
        for (int kk = 0; kk < DIM_; kk += 32) {
            bf16x8 bfr = *reinterpret_cast<const bf16x8*>(wrow + kk);
            bf16x8 a0 = *reinterpret_cast<const bf16x8*>(&As[abase + kk]);
            bf16x8 a1 = *reinterpret_cast<const bf16x8*>(&As[abase + 16 * 392 + kk]);
            bf16x8 a2 = *reinterpret_cast<const bf16x8*>(&As[abase + 32 * 392 + kk]);
            bf16x8 a3 = *reinterpret_cast<const bf16x8*>(&As[abase + 48 * 392 + kk]);
            acc0 = __builtin_amdgcn_mfma_f32_16x16x32_bf16(a0, bfr, acc0, 0, 0, 0);
            acc1 = __builtin_amdgcn_mfma_f32_16x16x32_bf16(a1, bfr, acc1, 0, 0, 0);
            acc2 = __builtin_amdgcn_mfma_f32_16x16x32_bf16(a2, bfr, acc2, 0, 0, 0);
            acc3 = __builtin_amdgcn_mfma_f32_16x16x32_bf16(a3, bfr, acc3, 0, 0, 0);
        }
        const float bjv = bf2f_us(bb[j]);
        const int head = j >> 5, hd = j & 31;
        f32x4 accs[4] = {acc0, acc1, acc2, acc3};
        #pragma unroll
        for (int rt = 0; rt < 4; ++rt) {
            #pragma unroll
            for (int r = 0; r < 4; ++r) {
                const int token = rt * 16 + quad * 4 + r;  // D: row=quad*4+reg, col=lane&15
                const float v = accs[rt][r] + bjv;
                if (wsel == 0) {
                    qws[(((size_t)lw * NH_ + head) * 64 + token) * 32 + hd] = __float2bfloat16(v * scale);
                } else if (wsel == 1) {
                    kws[(((size_t)lw * NH_ + head) * 64 + token) * 32 + hd] = __float2bfloat16(v);
                } else {
                    vws[(((size_t)lw * NH_ + head) * 32 + hd) * 64 + token] = __float2bfloat16(v);
                }
            }
        }
    }
}

// ---------------- windowed attention, one wave per (window, head) ----------------
__global__ __launch_bounds__(64) void attn_kernel(
    const __hip_bfloat16* __restrict__ qws, const __hip_bfloat16* __restrict__ kws,
    const __hip_bfloat16* __restrict__ vws, const float* __restrict__ biasmat,
    __hip_bfloat16* __restrict__ attnout, int wbase)
{
    __shared__ __align__(16) __hip_bfloat16 Pbuf[64 * 72];
    const int bid = blockIdx.x;
    const int lw = bid / NH_, h = bid - lw * NH_;
    const int w = wbase + lw;
    const int lane = threadIdx.x, col16 = lane & 15, quad = lane >> 4;
    const ushort* qp = reinterpret_cast<const ushort*>(qws) + ((size_t)lw * NH_ + h) * 64 * 32;
    const ushort* kp = reinterpret_cast<const ushort*>(kws) + ((size_t)lw * NH_ + h) * 64 * 32;
    const ushort* vp = reinterpret_cast<const ushort*>(vws) + ((size_t)lw * NH_ + h) * 32 * 64;

    bf16x8 aq[4], bk4[4];
    #pragma unroll
    for (int t = 0; t < 4; ++t) {
        aq[t]  = *reinterpret_cast<const bf16x8*>(qp + (t * 16 + col16) * 32 + quad * 8);
        bk4[t] = *reinterpret_cast<const bf16x8*>(kp + (t * 16 + col16) * 32 + quad * 8);
    }
    f32x4 S[4][4];
    #pragma unroll
    for (int rt = 0; rt < 4; ++rt) {
        #pragma unroll
        for (int ct = 0; ct < 4; ++ct) {
            f32x4 z = {0.f,0.f,0.f,0.f};
            S[rt][ct] = __builtin_amdgcn_mfma_f32_16x16x32_bf16(aq[rt], bk4[ct], z, 0, 0, 0);
        }
    }

    const int widx = w & 63, wr = widx >> 3, wc = widx & 7;
    #pragma unroll
    for (int ct = 0; ct < 4; ++ct) {
        const int jj = ct * 16 + col16;
        const int cntj = regioncnt(jj, wr, wc);
        #pragma unroll
        for (int rt = 0; rt < 4; ++rt) {
            #pragma unroll
            for (int r = 0; r < 4; ++r) {
                const int ii = rt * 16 + quad * 4 + r;
                float add = biasmat[h * 4096 + ii * 64 + jj];
                if (regioncnt(ii, wr, wc) != cntj) add -= 100.f;
                S[rt][ct][r] += add;
            }
        }
    }

    #pragma unroll
    for (int rt = 0; rt < 4; ++rt) {
        float rm[4], rs[4];
        #pragma unroll
        for (int r = 0; r < 4; ++r)
            rm[r] = fmaxf(fmaxf(S[rt][0][r], S[rt][1][r]), fmaxf(S[rt][2][r], S[rt][3][r]));
        #pragma unroll
        for (int d = 1; d <= 8; d <<= 1) {
            #pragma unroll
            for (int r = 0; r < 4; ++r) rm[r] = fmaxf(rm[r], __shfl_xor(rm[r], d, 64));
        }
        #pragma unroll
        for (int r = 0; r < 4; ++r) rs[r] = 0.f;
        #pragma unroll
        for (int ct = 0; ct < 4; ++ct) {
            #pragma unroll
            for (int r = 0; r < 4; ++r) {
                float p = __expf(S[rt][ct][r] - rm[r]);
                S[rt][ct][r] = p;
                rs[r] += p;
            }
        }
        #pragma unroll
        for (int d = 1; d <= 8; d <<= 1) {
            #pragma unroll
            for (int r = 0; r < 4; ++r) rs[r] += __shfl_xor(rs[r], d, 64);
        }
        #pragma unroll
        for (int ct = 0; ct < 4; ++ct) {
            #pragma unroll
            for (int r = 0; r < 4; ++r) {
                const float inv = 1.0f / rs[r];
                Pbuf[(rt * 16 + quad * 4 + r) * 72 + ct * 16 + col16] =
                    __float2bfloat16(S[rt][ct][r] * inv);
            }
        }
    }
    __syncthreads();

    f32x4 O[4][2];
    #pragma unroll
    for (int rt = 0; rt < 4; ++rt) {
        f32x4 z = {0.f,0.f,0.f,0.f};
        O[rt][0] = z; O[rt][1] = z;
    }
    const ushort* pb = reinterpret_cast<const ushort*>(Pbuf);
    #pragma unroll
    for (int ks = 0; ks < 2; ++ks) {
        bf16x8 bv0 = *reinterpret_cast<const bf16x8*>(vp + (col16)*64 + ks * 32 + quad * 8);
        bf16x8 bv1 = *reinterpret_cast<const bf16x8*>(vp + (16 + col16) * 64 + ks * 32 + quad * 8);
        #pragma unroll
        for (int rt = 0; rt < 4; ++rt) {
            bf16x8 ap = *reinterpret_cast<const bf16x8*>(pb + (rt * 16 + col16) * 72 + ks * 32 + quad * 8);
            O[rt][0] = __builtin_amdgcn_mfma_f32_16x16x32_bf16(ap, bv0, O[rt][0], 0, 0, 0);
            O[rt][1] = __builtin_amdgcn_mfma_f32_16x16x32_bf16(ap, bv1, O[rt][1], 0, 0, 0);
        }
    }
    __hip_bfloat16* op = attnout + (size_t)lw * 64 * DIM_ + h * 32;
    #pragma unroll
    for (int rt = 0; rt < 4; ++rt) {
        #pragma unroll
        for (int c2 = 0; c2 < 2; ++c2) {
            #pragma unroll
            for (int r = 0; r < 4; ++r) {
                const int token = rt * 16 + quad * 4 + r;
                op[token * DIM_ + c2 * 16 + col16] = __float2bfloat16(O[rt][c2][r]);
            }
        }
    }
}

// ---------------- output projection + window reverse + roll(+4,+4) ----------------
__global__ __launch_bounds__(256) void proj_kernel(
    const __hip_bfloat16* __restrict__ attnin, const ushort* __restrict__ wb,
    const int* __restrict__ flag, void* __restrict__ out, int wbase)
{
    __shared__ __align__(16) ushort As[64 * 392];
    const int lw = blockIdx.x;
    const int w = wbase + lw;
    const int b = w >> 6, widx = w & 63, wr = widx >> 3, wc = widx & 7;
    const int tid = threadIdx.x;
    const int isf32 = *flag;
    const ushort* ain = reinterpret_cast<const ushort*>(attnin) + (size_t)lw * 64 * DIM_;
    for (int c = tid; c < 64 * 48; c += 256) {
        int token = c / 48, chunk = c - token * 48;
        *reinterpret_cast<uint4*>(&As[token * 392 + chunk * 8]) =
            *reinterpret_cast<const uint4*>(ain + token * DIM_ + chunk * 8);
    }
    __syncthreads();

    const int lane = tid & 63, wave = tid >> 6;
    const int col16 = lane & 15, quad = lane >> 4;
    const ushort* woc = wb + 3 * 147456;
    const ushort* boc = wb + 589824 + 3 * 384;

    for (int s = wave; s < 24; s += 4) {
        const int j = s * 16 + col16;
        const ushort* wrow = woc + (size_t)j * DIM_ + quad * 8;
        const int abase = col16 * 392 + quad * 8;
        f32x4 acc0 = {0.f,0.f,0.f,0.f}, acc1 = acc0, acc2 = acc0, acc3 = acc0;
        #pragma unroll
        for (int kk = 0; kk < DIM_; kk += 32) {
            bf16x8 bfr = *reinterpret_cast<const bf16x8*>(wrow + kk);
            bf16x8 a0 = *reinterpret_cast<const bf16x8*>(&As[abase + kk]);
            bf16x8 a1 = *reinterpret_cast<const bf16x8*>(&As[abase + 16 * 392 + kk]);
            bf16x8 a2 = *reinterpret_cast<const bf16x8*>(&As[abase + 32 * 392 + kk]);
            bf16x8 a3 = *reinterpret_cast<const bf16x8*>(&As[abase + 48 * 392 + kk]);
            acc0 = __builtin_amdgcn_mfma_f32_16x16x32_bf16(a0, bfr, acc0, 0, 0, 0);
            acc1 = __builtin_amdgcn_mfma_f32_16x16x32_bf16(a1, bfr, acc1, 0, 0, 0);
            acc2 = __builtin_amdgcn_mfma_f32_16x16x32_bf16(a2, bfr, acc2, 0, 0, 0);
            acc3 = __builtin_amdgcn_mfma_f32_16x16x32_bf16(a3, bfr, acc3, 0, 0, 0);
        }
        const float bjv = bf2f_us(boc[j]);
        f32x4 accs[4] = {acc0, acc1, acc2, acc3};
        #pragma unroll
        for (int rt = 0; rt < 4; ++rt) {
            #pragma unroll
            for (int r = 0; r < 4; ++r) {
                const int token = rt * 16 + quad * 4 + r;
                const int orr = (wr * 8 + (token >> 3) + 4) & 63;
                const int occ = (wc * 8 + (token & 7) + 4) & 63;
                const size_t idx = (((size_t)b * 64 + orr) * 64 + occ) * DIM_ + j;
                const float v = accs[rt][r] + bjv;
                if (isf32) ((float*)out)[idx] = v;
                else       ((__hip_bfloat16*)out)[idx] = __float2bfloat16(v);
            }
        }
    }
}

extern "C" void kernel_launch(void* const* d_in, const int* in_sizes, int n_in,
                              void* d_out, int out_size, void* d_ws, size_t ws_size,
                              hipStream_t stream) {
    char* ws = (char*)d_ws;
    // ws layout (bytes):
    //   0        : int flag
    //   256      : ushort[594060] bf16 weights/biases/table (wq wk wv wo | bq bk bv bo | table)
    //   1189888  : float biasmat[12*4096]  (196608 B)
    //   1386496  : chunk buffers qws|kws|vws (each 6291456 B) | att (6291456 B)
    // total ~25.3 MB
    int*    flag    = (int*)ws;
    ushort* wb      = (ushort*)(ws + 256);
    float*  biasmat = (float*)(ws + 1189888);
    const size_t CQ = (size_t)WCHUNK * NH_ * 64 * 32 * 2;  // 6,291,456
    __hip_bfloat16* qws = (__hip_bfloat16*)(ws + 1386496);
    __hip_bfloat16* kws = (__hip_bfloat16*)(ws + 1386496 + CQ);
    __hip_bfloat16* vws = (__hip_bfloat16*)(ws + 1386496 + 2 * CQ);
    __hip_bfloat16* att = (__hip_bfloat16*)(ws + 1386496 + 3 * CQ);

    detect_kernel<<<dim3(1), dim3(64), 0, stream>>>((const ushort*)d_in[0], flag);
    convert_kernel<<<dim3(512), dim3(256), 0, stream>>>(
        d_in[1], d_in[3], d_in[5], d_in[7],
        d_in[2], d_in[4], d_in[6], d_in[8], d_in[9], flag, wb);
    bias_kernel<<<dim3(64), dim3(64), 0, stream>>>(wb + 591360, biasmat);

    for (int c = 0; c < 2048 / WCHUNK; ++c) {
        const int wbase = c * WCHUNK;
        qkv_kernel<<<dim3(WCHUNK), dim3(256), 0, stream>>>(d_in[0], wb, flag,
                                                           qws, kws, vws, wbase);
        attn_kernel<<<dim3(WCHUNK * NH_), dim3(64), 0, stream>>>(qws, kws, vws, biasmat,
                                                                 att, wbase);
        proj_kernel<<<dim3(WCHUNK), dim3(256), 0, stream>>>(att, wb, flag, d_out, wbase);
    }
}

// Round 4
// 1090.680 us; speedup vs baseline: 1.9631x; 1.9631x over previous
//
#include <hip/hip_runtime.h>
#include <hip/hip_bf16.h>

typedef short bf16x8 __attribute__((ext_vector_type(8)));
typedef float f32x4 __attribute__((ext_vector_type(4)));

#define NH_ 12
#define DIM_ 384

static __device__ __forceinline__ float bf2f_us(ushort u) {
    __hip_bfloat16 h; __builtin_memcpy(&h, &u, 2);
    return __bfloat162float(h);
}
static __device__ __forceinline__ ushort f2us(float f) {
    __hip_bfloat16 h = __float2bfloat16(f);
    ushort u; __builtin_memcpy(&u, &h, 2);
    return u;
}

static __device__ __forceinline__ int regioncnt(int t, int wr, int wc) {
    int rr = (wr == 7) ? (((t >> 3) < 4) ? 1 : 2) : 0;
    int cc = (wc == 7) ? (((t & 7) < 4) ? 1 : 2) : 0;
    return rr * 3 + cc;
}

// ---------------- convert f32 weights/biases/table -> bf16 in ws ----------------
// dst layout (ushort elements): wq[147456] wk wv wo | bq[384] bk bv bo | table[2700]
__global__ __launch_bounds__(256) void convert_kernel(
    const float* wq, const float* wk, const float* wv, const float* wo,
    const float* bq, const float* bk, const float* bv, const float* bo,
    const float* bt, ushort* __restrict__ dst)
{
    const int N = 594060;
    for (int i = blockIdx.x * 256 + threadIdx.x; i < N; i += gridDim.x * 256) {
        const float* src; int off;
        if (i < 589824) {
            int wsel = i / 147456; off = i - wsel * 147456;
            src = (wsel == 0) ? wq : (wsel == 1) ? wk : (wsel == 2) ? wv : wo;
        } else if (i < 591360) {
            int bsel = (i - 589824) / 384; off = (i - 589824) - bsel * 384;
            src = (bsel == 0) ? bq : (bsel == 1) ? bk : (bsel == 2) ? bv : bo;
        } else {
            off = i - 591360; src = bt;
        }
        dst[i] = f2us(src[off]);
    }
}

// ---------------- relative-position bias matrix (12,64,64) fp32 ----------------
__global__ void bias_kernel(const ushort* __restrict__ tablec, float* __restrict__ biasmat) {
    int i = blockIdx.x;   // row token
    int j = threadIdx.x;  // col token
    int idx = ((i >> 3) - (j >> 3) + 7) * 15 + ((i & 7) - (j & 7) + 7);
    #pragma unroll
    for (int h = 0; h < NH_; ++h)
        biasmat[h * 4096 + i * 64 + j] = bf2f_us(tablec[idx * NH_ + h]);
}

// ---------------- QKV projection per window ----------------
__global__ __launch_bounds__(256) void qkv_kernel(
    const float* __restrict__ x, const ushort* __restrict__ wb,
    __hip_bfloat16* __restrict__ qws, __hip_bfloat16* __restrict__ kws,
    __hip_bfloat16* __restrict__ vws, int wbase)
{
    __shared__ __align__(16) ushort As[64 * 392];
    const int lw = blockIdx.x;
    const int w = wbase + lw;
    const int b = w >> 6, widx = w & 63, wr = widx >> 3, wc = widx & 7;
    const int tid = threadIdx.x;

    // stage shifted window tokens into LDS (gather with roll(-4,-4)), f32 -> bf16
    for (int c = tid; c < 64 * 96; c += 256) {   // 4 floats per chunk
        int token = c / 96, chunk = c - token * 96;
        int orr = (wr * 8 + (token >> 3) + 4) & 63;
        int occ = (wc * 8 + (token & 7) + 4) & 63;
        const float4 v = *reinterpret_cast<const float4*>(
            x + (((size_t)b * 64 + orr) * 64 + occ) * DIM_ + chunk * 4);
        ushort4 u; u.x = f2us(v.x); u.y = f2us(v.y); u.z = f2us(v.z); u.w = f2us(v.w);
        *reinterpret_cast<ushort4*>(&As[token * 392 + chunk * 4]) = u;
    }
    __syncthreads();

    const int lane = tid & 63, wave = tid >> 6;
    const int col16 = lane & 15, quad = lane >> 4;
    const float scale = 0.17677669529663687f;  // 32^-0.5
    const ushort* bias_all = wb + 589824;      // bq,bk,bv,bo each 384

    for (int s = wave; s < 72; s += 4) {  // [0,24)=q [24,48)=k [48,72)=v
        const int wsel = s / 24;
        const int j0 = (s - wsel * 24) * 16;
        const ushort* W = wb + (size_t)wsel * 147456;        // wq,wk,wv
        const ushort* bb = bias_all + wsel * 384;
        const int j = j0 + col16;
        const ushort* wrow = W + (size_t)j * DIM_ + quad * 8;
        const int abase = col16 * 392 + quad * 8;
        f32x4 acc0 = {0.f,0.f,0.f,0.f}, acc1 = acc0, acc2 = acc0, acc3 = acc0;
        #pragma unroll
        for (int kk = 0; kk < DIM_; kk += 32) {
            bf16x8 bfr = *reinterpret_cast<const bf16x8*>(wrow + kk);
            bf16x8 a0 = *reinterpret_cast<const bf16x8*>(&As[abase + kk]);
            bf16x8 a1 = *reinterpret_cast<const bf16x8*>(&As[abase + 16 * 392 + kk]);
            bf16x8 a2 = *reinterpret_cast<const bf16x8*>(&As[abase + 32 * 392 + kk]);
            bf16x8 a3 = *reinterpret_cast<const bf16x8*>(&As[abase + 48 * 392 + kk]);
            acc0 = __builtin_amdgcn_mfma_f32_16x16x32_bf16(a0, bfr, acc0, 0, 0, 0);
            acc1 = __builtin_amdgcn_mfma_f32_16x16x32_bf16(a1, bfr, acc1, 0, 0, 0);
            acc2 = __builtin_amdgcn_mfma_f32_16x16x32_bf16(a2, bfr, acc2, 0, 0, 0);
            acc3 = __builtin_amdgcn_mfma_f32_16x16x32_bf16(a3, bfr, acc3, 0, 0, 0);
        }
        const float bjv = bf2f_us(bb[j]);
        const int head = j >> 5, hd = j & 31;
        f32x4 accs[4] = {acc0, acc1, acc2, acc3};
        #pragma unroll
        for (int rt = 0; rt < 4; ++rt) {
            #pragma unroll
            for (int r = 0; r < 4; ++r) {
                const int token = rt * 16 + quad * 4 + r;  // D: row=quad*4+reg, col=lane&15
                const float v = accs[rt][r] + bjv;
                if (wsel == 0) {
                    qws[(((size_t)lw * NH_ + head) * 64 + token) * 32 + hd] = __float2bfloat16(v * scale);
                } else if (wsel == 1) {
                    kws[(((size_t)lw * NH_ + head) * 64 + token) * 32 + hd] = __float2bfloat16(v);
                } else {
                    vws[(((size_t)lw * NH_ + head) * 32 + hd) * 64 + token] = __float2bfloat16(v);
                }
            }
        }
    }
}

// ---------------- windowed attention, one wave per (window, head) ----------------
__global__ __launch_bounds__(64) void attn_kernel(
    const __hip_bfloat16* __restrict__ qws, const __hip_bfloat16* __restrict__ kws,
    const __hip_bfloat16* __restrict__ vws, const float* __restrict__ biasmat,
    __hip_bfloat16* __restrict__ attnout, int wbase)
{
    __shared__ __align__(16) __hip_bfloat16 Pbuf[64 * 72];
    const int bid = blockIdx.x;
    const int lw = bid / NH_, h = bid - lw * NH_;
    const int w = wbase + lw;
    const int lane = threadIdx.x, col16 = lane & 15, quad = lane >> 4;
    const ushort* qp = reinterpret_cast<const ushort*>(qws) + ((size_t)lw * NH_ + h) * 64 * 32;
    const ushort* kp = reinterpret_cast<const ushort*>(kws) + ((size_t)lw * NH_ + h) * 64 * 32;
    const ushort* vp = reinterpret_cast<const ushort*>(vws) + ((size_t)lw * NH_ + h) * 32 * 64;

    bf16x8 aq[4], bk4[4];
    #pragma unroll
    for (int t = 0; t < 4; ++t) {
        aq[t]  = *reinterpret_cast<const bf16x8*>(qp + (t * 16 + col16) * 32 + quad * 8);
        bk4[t] = *reinterpret_cast<const bf16x8*>(kp + (t * 16 + col16) * 32 + quad * 8);
    }
    f32x4 S[4][4];
    #pragma unroll
    for (int rt = 0; rt < 4; ++rt) {
        #pragma unroll
        for (int ct = 0; ct < 4; ++ct) {
            f32x4 z = {0.f,0.f,0.f,0.f};
            S[rt][ct] = __builtin_amdgcn_mfma_f32_16x16x32_bf16(aq[rt], bk4[ct], z, 0, 0, 0);
        }
    }

    const int widx = w & 63, wr = widx >> 3, wc = widx & 7;
    #pragma unroll
    for (int ct = 0; ct < 4; ++ct) {
        const int jj = ct * 16 + col16;
        const int cntj = regioncnt(jj, wr, wc);
        #pragma unroll
        for (int rt = 0; rt < 4; ++rt) {
            #pragma unroll
            for (int r = 0; r < 4; ++r) {
                const int ii = rt * 16 + quad * 4 + r;
                float add = biasmat[h * 4096 + ii * 64 + jj];
                if (regioncnt(ii, wr, wc) != cntj) add -= 100.f;
                S[rt][ct][r] += add;
            }
        }
    }

    #pragma unroll
    for (int rt = 0; rt < 4; ++rt) {
        float rm[4], rs[4];
        #pragma unroll
        for (int r = 0; r < 4; ++r)
            rm[r] = fmaxf(fmaxf(S[rt][0][r], S[rt][1][r]), fmaxf(S[rt][2][r], S[rt][3][r]));
        #pragma unroll
        for (int d = 1; d <= 8; d <<= 1) {
            #pragma unroll
            for (int r = 0; r < 4; ++r) rm[r] = fmaxf(rm[r], __shfl_xor(rm[r], d, 64));
        }
        #pragma unroll
        for (int r = 0; r < 4; ++r) rs[r] = 0.f;
        #pragma unroll
        for (int ct = 0; ct < 4; ++ct) {
            #pragma unroll
            for (int r = 0; r < 4; ++r) {
                float p = __expf(S[rt][ct][r] - rm[r]);
                S[rt][ct][r] = p;
                rs[r] += p;
            }
        }
        #pragma unroll
        for (int d = 1; d <= 8; d <<= 1) {
            #pragma unroll
            for (int r = 0; r < 4; ++r) rs[r] += __shfl_xor(rs[r], d, 64);
        }
        #pragma unroll
        for (int ct = 0; ct < 4; ++ct) {
            #pragma unroll
            for (int r = 0; r < 4; ++r) {
                const float inv = 1.0f / rs[r];
                Pbuf[(rt * 16 + quad * 4 + r) * 72 + ct * 16 + col16] =
                    __float2bfloat16(S[rt][ct][r] * inv);
            }
        }
    }
    __syncthreads();

    f32x4 O[4][2];
    #pragma unroll
    for (int rt = 0; rt < 4; ++rt) {
        f32x4 z = {0.f,0.f,0.f,0.f};
        O[rt][0] = z; O[rt][1] = z;
    }
    const ushort* pb = reinterpret_cast<const ushort*>(Pbuf);
    #pragma unroll
    for (int ks = 0; ks < 2; ++ks) {
        bf16x8 bv0 = *reinterpret_cast<const bf16x8*>(vp + (col16)*64 + ks * 32 + quad * 8);
        bf16x8 bv1 = *reinterpret_cast<const bf16x8*>(vp + (16 + col16) * 64 + ks * 32 + quad * 8);
        #pragma unroll
        for (int rt = 0; rt < 4; ++rt) {
            bf16x8 ap = *reinterpret_cast<const bf16x8*>(pb + (rt * 16 + col16) * 72 + ks * 32 + quad * 8);
            O[rt][0] = __builtin_amdgcn_mfma_f32_16x16x32_bf16(ap, bv0, O[rt][0], 0, 0, 0);
            O[rt][1] = __builtin_amdgcn_mfma_f32_16x16x32_bf16(ap, bv1, O[rt][1], 0, 0, 0);
        }
    }
    __hip_bfloat16* op = attnout + (size_t)lw * 64 * DIM_ + h * 32;
    #pragma unroll
    for (int rt = 0; rt < 4; ++rt) {
        #pragma unroll
        for (int c2 = 0; c2 < 2; ++c2) {
            #pragma unroll
            for (int r = 0; r < 4; ++r) {
                const int token = rt * 16 + quad * 4 + r;
                op[token * DIM_ + c2 * 16 + col16] = __float2bfloat16(O[rt][c2][r]);
            }
        }
    }
}

// ---------------- output projection + window reverse + roll(+4,+4), f32 out ----------------
__global__ __launch_bounds__(256) void proj_kernel(
    const __hip_bfloat16* __restrict__ attnin, const ushort* __restrict__ wb,
    float* __restrict__ out, int wbase)
{
    __shared__ __align__(16) ushort As[64 * 392];
    const int lw = blockIdx.x;
    const int w = wbase + lw;
    const int b = w >> 6, widx = w & 63, wr = widx >> 3, wc = widx & 7;
    const int tid = threadIdx.x;
    const ushort* ain = reinterpret_cast<const ushort*>(attnin) + (size_t)lw * 64 * DIM_;
    for (int c = tid; c < 64 * 48; c += 256) {
        int token = c / 48, chunk = c - token * 48;
        *reinterpret_cast<uint4*>(&As[token * 392 + chunk * 8]) =
            *reinterpret_cast<const uint4*>(ain + token * DIM_ + chunk * 8);
    }
    __syncthreads();

    const int lane = tid & 63, wave = tid >> 6;
    const int col16 = lane & 15, quad = lane >> 4;
    const ushort* woc = wb + 3 * 147456;
    const ushort* boc = wb + 589824 + 3 * 384;

    for (int s = wave; s < 24; s += 4) {
        const int j = s * 16 + col16;
        const ushort* wrow = woc + (size_t)j * DIM_ + quad * 8;
        const int abase = col16 * 392 + quad * 8;
        f32x4 acc0 = {0.f,0.f,0.f,0.f}, acc1 = acc0, acc2 = acc0, acc3 = acc0;
        #pragma unroll
        for (int kk = 0; kk < DIM_; kk += 32) {
            bf16x8 bfr = *reinterpret_cast<const bf16x8*>(wrow + kk);
            bf16x8 a0 = *reinterpret_cast<const bf16x8*>(&As[abase + kk]);
            bf16x8 a1 = *reinterpret_cast<const bf16x8*>(&As[abase + 16 * 392 + kk]);
            bf16x8 a2 = *reinterpret_cast<const bf16x8*>(&As[abase + 32 * 392 + kk]);
            bf16x8 a3 = *reinterpret_cast<const bf16x8*>(&As[abase + 48 * 392 + kk]);
            acc0 = __builtin_amdgcn_mfma_f32_16x16x32_bf16(a0, bfr, acc0, 0, 0, 0);
            acc1 = __builtin_amdgcn_mfma_f32_16x16x32_bf16(a1, bfr, acc1, 0, 0, 0);
            acc2 = __builtin_amdgcn_mfma_f32_16x16x32_bf16(a2, bfr, acc2, 0, 0, 0);
            acc3 = __builtin_amdgcn_mfma_f32_16x16x32_bf16(a3, bfr, acc3, 0, 0, 0);
        }
        const float bjv = bf2f_us(boc[j]);
        f32x4 accs[4] = {acc0, acc1, acc2, acc3};
        #pragma unroll
        for (int rt = 0; rt < 4; ++rt) {
            #pragma unroll
            for (int r = 0; r < 4; ++r) {
                const int token = rt * 16 + quad * 4 + r;
                const int orr = (wr * 8 + (token >> 3) + 4) & 63;
                const int occ = (wc * 8 + (token & 7) + 4) & 63;
                out[(((size_t)b * 64 + orr) * 64 + occ) * DIM_ + j] = accs[rt][r] + bjv;
            }
        }
    }
}

extern "C" void kernel_launch(void* const* d_in, const int* in_sizes, int n_in,
                              void* d_out, int out_size, void* d_ws, size_t ws_size,
                              hipStream_t stream) {
    const float* x = (const float*)d_in[0];
    float* out = (float*)d_out;
    char* ws = (char*)d_ws;

    // ws layout (bytes):
    //   0        : ushort[594060] bf16 weights/biases/table (1,188,120 B)
    //   1188352  : float biasmat[12*4096]  (196,608 B)
    //   1384960  : chunk buffers qws|kws|vws|att (each WCHUNK*49152 B)
    ushort* wb      = (ushort*)ws;
    float*  biasmat = (float*)(ws + 1188352);
    const size_t FIXED = 1384960;

    // adaptive chunking: largest windows-per-chunk that fits ws (constant per process)
    int wchunk = 128;
    const int cands[4] = {2048, 1024, 512, 256};
    for (int i = 0; i < 4; ++i) {
        if (FIXED + (size_t)cands[i] * 4 * 49152 <= ws_size) { wchunk = cands[i]; break; }
    }
    const size_t CQ = (size_t)wchunk * NH_ * 64 * 32 * 2;
    __hip_bfloat16* qws = (__hip_bfloat16*)(ws + FIXED);
    __hip_bfloat16* kws = (__hip_bfloat16*)(ws + FIXED + CQ);
    __hip_bfloat16* vws = (__hip_bfloat16*)(ws + FIXED + 2 * CQ);
    __hip_bfloat16* att = (__hip_bfloat16*)(ws + FIXED + 3 * CQ);

    convert_kernel<<<dim3(512), dim3(256), 0, stream>>>(
        (const float*)d_in[1], (const float*)d_in[3], (const float*)d_in[5], (const float*)d_in[7],
        (const float*)d_in[2], (const float*)d_in[4], (const float*)d_in[6], (const float*)d_in[8],
        (const float*)d_in[9], wb);
    bias_kernel<<<dim3(64), dim3(64), 0, stream>>>(wb + 591360, biasmat);

    for (int c = 0; c < 2048 / wchunk; ++c) {
        const int wbase = c * wchunk;
        qkv_kernel<<<dim3(wchunk), dim3(256), 0, stream>>>(x, wb, qws, kws, vws, wbase);
        attn_kernel<<<dim3(wchunk * NH_), dim3(64), 0, stream>>>(qws, kws, vws, biasmat, att, wbase);
        proj_kernel<<<dim3(wchunk), dim3(256), 0, stream>>>(att, wb, out, wbase);
    }
}